// Round 3
// baseline (1575.536 us; speedup 1.0000x reference)
//
#include <hip/hip_runtime.h>
#include <hip/hip_bf16.h>

typedef __bf16 bf16;
typedef float f32x4 __attribute__((ext_vector_type(4)));

#define BB 64
#define EMB 256
#define UNITS 512
#define POI 5000
#define KCAT 1280
#define L2E 1.4426950408889634f

__device__ __forceinline__ float rcp_(float x){ return __builtin_amdgcn_rcpf(x); }
__device__ __forceinline__ float exp2_(float x){ return __builtin_amdgcn_exp2f(x); }

template<bool F> __device__ __forceinline__ float ld(const void* p, size_t i){
  return F ? ((const float*)p)[i] : (float)((const bf16*)p)[i];
}
template<bool F> __device__ __forceinline__ void st(void* p, size_t i, float v){
  if(F) ((float*)p)[i] = v; else ((bf16*)p)[i] = (bf16)v;
}

// ---- dtype probe: fp32 data read as words has uniform low-16 "bf16 exponent" field;
// real bf16 N(0,1) data never has exponent field > 140 (would mean |x| >= 2^13).
__global__ void k_flag(const unsigned int* q, int* flag){
  __shared__ int cnt[256];
  int t = threadIdx.x, c = 0;
  for(int i=t;i<1024;i+=256){
    unsigned e = (q[i] >> 7) & 0xFFu;
    c += (e > 140u) ? 1 : 0;
  }
  cnt[t]=c; __syncthreads();
  for(int o=128;o>0;o>>=1){ if(t<o) cnt[t]+=cnt[t+o]; __syncthreads(); }
  if(t==0) *flag = (cnt[0] > 64) ? 1 : 0;
}

// ---- x1=[emb[x[b]]|query[b]], h0->fp32, outc[768:1280]=cat_dec
template<bool F> __device__ void prep_body(const int* x, const void* query, const void* emb,
    const void* h0, const void* catd, float* x1, float* h0f, float* outc){
  int b = blockIdx.x, t = threadIdx.x;  // 256 thr
  int row = x[b];
  x1[b*512 + t]       = ld<F>(emb, (size_t)row*EMB + t);
  x1[b*512 + 256 + t] = ld<F>(query, (size_t)b*256 + t);
  h0f[b*512 + t]       = ld<F>(h0, (size_t)b*512 + t);
  h0f[b*512 + 256 + t] = ld<F>(h0, (size_t)b*512 + 256 + t);
  outc[b*KCAT + 768 + t]       = ld<F>(catd, (size_t)b*512 + t);
  outc[b*KCAT + 768 + 256 + t] = ld<F>(catd, (size_t)b*512 + 256 + t);
}
__global__ void k_prep(const int* x, const void* query, const void* emb, const void* h0,
                       const void* catd, float* x1, float* h0f, float* outc, const int* flag){
  if(*flag) prep_body<true>(x,query,emb,h0,catd,x1,h0f,outc);
  else      prep_body<false>(x,query,emb,h0,catd,x1,h0f,outc);
}

// ---- C[64,N] = A[64,K] @ B[K,N], fp32 A in ws, B dual. 256 thr, 64-col tiles.
template<bool F> __device__ void gemm_body(const float* A, const void* B, float* C, int K, int N){
  __shared__ float As[64][65];
  int t = threadIdx.x;
  int col = blockIdx.x*64 + (t & 63);
  int r0 = (t >> 6) * 16;
  int colc = col < N ? col : N-1;
  float acc[16];
#pragma unroll
  for(int r=0;r<16;r++) acc[r]=0.f;
  for(int kc=0; kc<K; kc+=64){
    __syncthreads();
    for(int i=t;i<4096;i+=256){ int r=i>>6, j=i&63; As[r][j] = A[(size_t)r*K + kc + j]; }
    __syncthreads();
#pragma unroll 8
    for(int j=0;j<64;j++){
      float bv = ld<F>(B, (size_t)(kc+j)*N + colc);
#pragma unroll
      for(int r=0;r<16;r++) acc[r] += As[r0+r][j]*bv;
    }
  }
  if(col < N){
#pragma unroll
    for(int r=0;r<16;r++) C[(size_t)(r0+r)*N + col] = acc[r];
  }
}
__global__ __launch_bounds__(256) void k_gemm64(const float* A, const void* B, float* C,
                                                int K, int N, const int* flag){
  if(*flag) gemm_body<true>(A,B,C,K,N); else gemm_body<false>(A,B,C,K,N);
}

// ---- GRU gates (keras reset_after=True, z/r/h)
template<bool F> __device__ void gates_body(const float* xm, const float* hm, const void* bias,
    const float* h0f, float* hn, float* outc, void* dout){
  int b = blockIdx.x, u = threadIdx.x;  // 512 thr
  const float* xr = xm + b*1536; const float* hr = hm + b*1536;
  float xz = xr[u]      + ld<F>(bias, u);
  float xg = xr[512+u]  + ld<F>(bias, 512+u);
  float xh = xr[1024+u] + ld<F>(bias, 1024+u);
  float hz = hr[u]      + ld<F>(bias, 1536+u);
  float hg = hr[512+u]  + ld<F>(bias, 2048+u);
  float hh = hr[1024+u] + ld<F>(bias, 2560+u);
  float z = rcp_(1.f + exp2_(-L2E*(xz+hz)));
  float r = rcp_(1.f + exp2_(-L2E*(xg+hg)));
  float ca = xh + r*hh;
  ca = fminf(fmaxf(ca, -15.f), 15.f);
  float e = exp2_(2.f*L2E*ca);
  float hc = (e - 1.f)*rcp_(e + 1.f);
  float h = h0f[b*512+u];
  float v = z*h + (1.f - z)*hc;
  hn[b*512+u] = v;
  outc[b*KCAT + 256 + u] = v;
  st<F>(dout, (size_t)POI*BB + (size_t)b*512 + u, v);              // state
  st<F>(dout, (size_t)POI*BB + (size_t)BB*512 + (size_t)b*512 + u, v); // output_
}
__global__ void k_gates(const float* xm, const float* hm, const void* bias, const float* h0f,
                        float* hn, float* outc, void* dout, const int* flag){
  if(*flag) gates_body<true>(xm,hm,bias,h0f,hn,outc,dout);
  else      gates_body<false>(xm,hm,bias,h0f,hn,outc,dout);
}

// ---- Eq = exp2(clamp(2*log2e*(qv + W2b))) in place
template<bool F> __device__ void expq_body(float* qv, const void* W2b){
  int i = blockIdx.x*512 + threadIdx.x;
  int n = i & 511;
  float v = (qv[i] + ld<F>(W2b, n)) * (2.f*L2E);
  qv[i] = exp2_(fminf(fmaxf(v, -40.f), 40.f));
}
__global__ void k_expq(float* qv, const void* W2b, const int* flag){
  if(*flag) expq_body<true>(qv,W2b); else expq_body<false>(qv,W2b);
}

// ---- fused vproj+score, 16 poi rows/block.
// stage1: Ev[16][512]=exp(2*(emb@W1+b1)) in LDS (fp32 vector GEMM)
// stage2: sc[b][p] = sum_u Vw[u]/(Ev[p][u]*Eq[b][u]+1)   (tanh identity in k_softmax)
template<bool F> __device__ void vscore_body(const void* emb, const void* W1, const void* W1b,
    const float* Eq, const void* Vw, float* sc){
  __shared__ float evs[16][516];
  __shared__ float buf[4866];      // stage1: At = buf[0:4096] (16x256); stage2: Qs = buf[0:4352] (64x68); vws = buf[4352:4864]
  float (*At)[256] = (float(*)[256])buf;
  float (*Qs)[68]  = (float(*)[68])buf;
  float* vws = buf + 4352;
  int t = threadIdx.x;
  int p0 = blockIdx.x * 16;
  for(int i=t;i<4096;i+=256){
    int r = i>>8, k = i&255;
    int pr = p0 + r; if(pr > POI-1) pr = POI-1;
    At[r][k] = ld<F>(emb, (size_t)pr*EMB + k);
  }
  __syncthreads();
  float a0[16], a1[16];
#pragma unroll
  for(int r=0;r<16;r++){ a0[r]=0.f; a1[r]=0.f; }
  for(int k=0;k<256;k++){
    float b0 = ld<F>(W1, (size_t)k*UNITS + t);
    float b1 = ld<F>(W1, (size_t)k*UNITS + t + 256);
#pragma unroll
    for(int r=0;r<16;r++){ a0[r] += At[r][k]*b0; a1[r] += At[r][k]*b1; }
  }
  float bn0 = ld<F>(W1b, t), bn1 = ld<F>(W1b, t+256);
#pragma unroll
  for(int r=0;r<16;r++){
    float v0 = (a0[r]+bn0)*(2.f*L2E); v0 = fminf(fmaxf(v0,-40.f),40.f);
    evs[r][t] = exp2_(v0);
    float v1 = (a1[r]+bn1)*(2.f*L2E); v1 = fminf(fmaxf(v1,-40.f),40.f);
    evs[r][t+256] = exp2_(v1);
  }
  int tp = t & 7, tb = t >> 3;
  float s00=0.f, s01=0.f, s10=0.f, s11=0.f;
  for(int c=0;c<8;c++){
    __syncthreads();                 // c=0: At dead + evs complete; c>0: Qs consumers done
    int ub = c*64;
    for(int i=t;i<4096;i+=256){ int b=i>>6, u=i&63; Qs[b][u] = Eq[b*UNITS + ub + u]; }
    if(c==0){ vws[t] = ld<F>(Vw, t); vws[t+256] = ld<F>(Vw, t+256); }
    __syncthreads();
#pragma unroll
    for(int u4=0;u4<16;u4++){
      f32x4 e0 = *(f32x4*)&evs[2*tp][ub+u4*4];
      f32x4 e1 = *(f32x4*)&evs[2*tp+1][ub+u4*4];
      f32x4 q0 = *(f32x4*)&Qs[2*tb][u4*4];
      f32x4 q1 = *(f32x4*)&Qs[2*tb+1][u4*4];
      f32x4 w4 = *(f32x4*)&vws[ub+u4*4];
#pragma unroll
      for(int e=0;e<4;e++){
        float wv = w4[e];
        s00 += wv * rcp_(e0[e]*q0[e] + 1.f);
        s01 += wv * rcp_(e0[e]*q1[e] + 1.f);
        s10 += wv * rcp_(e1[e]*q0[e] + 1.f);
        s11 += wv * rcp_(e1[e]*q1[e] + 1.f);
      }
    }
  }
  int pA = p0 + 2*tp, bA = 2*tb;
  if(pA < POI)  { sc[(size_t)bA*POI + pA]   = s00; sc[(size_t)(bA+1)*POI + pA]   = s01; }
  if(pA+1 < POI){ sc[(size_t)bA*POI + pA+1] = s10; sc[(size_t)(bA+1)*POI + pA+1] = s11; }
}
__global__ __launch_bounds__(256) void k_vscore(const void* emb, const void* W1, const void* W1b,
    const float* Eq, const void* Vw, float* sc, const int* flag){
  if(*flag) vscore_body<true>(emb,W1,W1b,Eq,Vw,sc);
  else      vscore_body<false>(emb,W1,W1b,Eq,Vw,sc);
}

// ---- per-b: s = SW - 2*sc; softmax; unnormalized w back into sc, 1/sum into inv
template<bool F> __device__ void softmax_body(float* scA, const void* Vw, float* inv){
  __shared__ float red[256];
  int b = blockIdx.x, t = threadIdx.x;
  red[t] = ld<F>(Vw, t) + ld<F>(Vw, t+256);
  __syncthreads();
  for(int o=128;o>0;o>>=1){ if(t<o) red[t]+=red[t+o]; __syncthreads(); }
  float SW = red[0]; __syncthreads();
  float* sA = scA + (size_t)b*POI;
  float mx = -3.4e38f;
  for(int p=t;p<POI;p+=256){
    float s = SW - 2.f*sA[p];
    sA[p] = s;
    mx = fmaxf(mx, s);
  }
  red[t] = mx; __syncthreads();
  for(int o=128;o>0;o>>=1){ if(t<o) red[t]=fmaxf(red[t],red[t+o]); __syncthreads(); }
  float M = red[0]; __syncthreads();
  float sum = 0.f;
  for(int p=t;p<POI;p+=256){
    float wv = exp2_((sA[p] - M)*L2E);
    sA[p] = wv;
    sum += wv;
  }
  red[t] = sum; __syncthreads();
  for(int o=128;o>0;o>>=1){ if(t<o) red[t]+=red[t+o]; __syncthreads(); }
  if(t==0) inv[b] = rcp_(red[0]);
}
__global__ void k_softmax(float* sc, const void* Vw, float* inv, const int* flag){
  if(*flag) softmax_body<true>(sc,Vw,inv); else softmax_body<false>(sc,Vw,inv);
}

// ---- context[b] = (sum_p w[p]*emb[p,:]) * inv[b] -> outc[b][0:256]
template<bool F> __device__ void ctx_body(const float* w, const void* emb, const float* inv, float* outc){
  __shared__ float sh[4][256];
  int b = blockIdx.x;
  int pg = threadIdx.x >> 8, c = threadIdx.x & 255;
  const float* wb = w + (size_t)b*POI;
  float acc = 0.f;
  for(int p = pg; p < POI; p += 4)
    acc += wb[p] * ld<F>(emb, (size_t)p*EMB + c);
  sh[pg][c] = acc; __syncthreads();
  if(pg == 0)
    outc[b*KCAT + c] = (sh[0][c]+sh[1][c]+sh[2][c]+sh[3][c]) * inv[b];
}
__global__ __launch_bounds__(1024) void k_context(const float* w, const void* emb,
    const float* inv, float* outc, const int* flag){
  if(*flag) ctx_body<true>(w,emb,inv,outc); else ctx_body<false>(w,emb,inv,outc);
}

// ---- logits = outc @ fc_w + fc_b -> d_out (dual store)
template<bool F> __device__ void logits_body(const float* A, const void* Bw, const void* fcb, void* out){
  __shared__ float As[64][65];
  int t = threadIdx.x;
  int col = blockIdx.x*64 + (t & 63);
  int r0 = (t >> 6) * 16;
  int colc = col < POI ? col : POI-1;
  float acc[16];
#pragma unroll
  for(int r=0;r<16;r++) acc[r]=0.f;
  for(int kc=0; kc<KCAT; kc+=64){
    __syncthreads();
    for(int i=t;i<4096;i+=256){ int r=i>>6, j=i&63; As[r][j] = A[(size_t)r*KCAT + kc + j]; }
    __syncthreads();
#pragma unroll 8
    for(int j=0;j<64;j++){
      float bv = ld<F>(Bw, (size_t)(kc+j)*POI + colc);
#pragma unroll
      for(int r=0;r<16;r++) acc[r] += As[r0+r][j]*bv;
    }
  }
  if(col < POI){
    float bn = ld<F>(fcb, col);
#pragma unroll
    for(int r=0;r<16;r++) st<F>(out, (size_t)(r0+r)*POI + col, acc[r]+bn);
  }
}
__global__ __launch_bounds__(256) void k_logits(const float* A, const void* Bw, const void* fcb,
                                                void* out, const int* flag){
  if(*flag) logits_body<true>(A,Bw,fcb,out); else logits_body<false>(A,Bw,fcb,out);
}

extern "C" void kernel_launch(void* const* d_in, const int* in_sizes, int n_in,
                              void* d_out, int out_size, void* d_ws, size_t ws_size,
                              hipStream_t stream){
  const int*  x     = (const int*)d_in[0];
  const void* query = d_in[1];
  const void* emb   = d_in[2];
  // d_in[3] A_hat unused by reference
  const void* h0    = d_in[4];
  const void* catd  = d_in[5];
  const void* gruK  = d_in[6];
  const void* gruR  = d_in[7];
  const void* gruB  = d_in[8];
  const void* W1    = d_in[9];
  const void* W1b   = d_in[10];
  const void* W2    = d_in[11];
  const void* W2b   = d_in[12];
  const void* Vw    = d_in[13];
  // d_in[14] V_b: softmax-invariant, dropped
  const void* fcw   = d_in[15];
  const void* fcb   = d_in[16];

  char* ws = (char*)d_ws;
  size_t off = 0;
  auto alloc = [&](size_t bytes)->void*{ void* p = ws + off; off += (bytes + 255) & ~(size_t)255; return p; };
  int*   flag = (int*)  alloc(4);
  float* x1   = (float*)alloc((size_t)BB*512*4);
  float* h0f  = (float*)alloc((size_t)BB*512*4);
  float* outc = (float*)alloc((size_t)BB*KCAT*4);
  float* xm   = (float*)alloc((size_t)BB*1536*4);
  float* hm   = (float*)alloc((size_t)BB*1536*4);
  float* hn   = (float*)alloc((size_t)BB*512*4);
  float* qv   = (float*)alloc((size_t)BB*512*4);
  float* sc   = (float*)alloc((size_t)BB*POI*4);
  float* inv  = (float*)alloc((size_t)BB*4);
  // total ~2.9 MB

  k_flag   <<<1, 256, 0, stream>>>((const unsigned int*)query, flag);
  k_prep   <<<BB, 256, 0, stream>>>(x, query, emb, h0, catd, x1, h0f, outc, flag);
  k_gemm64 <<<24, 256, 0, stream>>>(x1, gruK, xm, 512, 1536, flag);
  k_gemm64 <<<24, 256, 0, stream>>>(h0f, gruR, hm, 512, 1536, flag);
  k_gates  <<<BB, 512, 0, stream>>>(xm, hm, gruB, h0f, hn, outc, d_out, flag);
  k_gemm64 <<<8, 256, 0, stream>>>(hn, W2, qv, 512, 512, flag);
  k_expq   <<<BB, 512, 0, stream>>>(qv, W2b, flag);
  k_vscore <<<313, 256, 0, stream>>>(emb, W1, W1b, qv, Vw, sc, flag);
  k_softmax<<<BB, 256, 0, stream>>>(sc, Vw, inv, flag);
  k_context<<<BB, 1024, 0, stream>>>(sc, emb, inv, outc, flag);
  k_logits <<<79, 256, 0, stream>>>(outc, fcw, fcb, d_out, flag);
}

// Round 4
// 252.813 us; speedup vs baseline: 6.2320x; 6.2320x over previous
//
#include <hip/hip_runtime.h>
#include <hip/hip_bf16.h>

typedef __bf16 bf16;
typedef __bf16 bf16x8 __attribute__((ext_vector_type(8)));
typedef float f32x4 __attribute__((ext_vector_type(4)));

#define BB 64
#define EMB 256
#define UNITS 512
#define POI 5000
#define KCAT 1280
#define SCLD 5024   // sc row stride (5000 padded to x32)
#define L2E 1.4426950408889634f

__device__ __forceinline__ float rcp_(float x){ return __builtin_amdgcn_rcpf(x); }
__device__ __forceinline__ float exp2_(float x){ return __builtin_amdgcn_exp2f(x); }

// ---- one 16x16x(K) MFMA C-tile from fp32 sources, on-the-fly bf16 cvt.
// A fp32 row-major [*, lda]: lane -> A[mr][q*8+j] (two f32x4 loads).
// B fp32 row-major [K, ldb]: lane -> B[q*8+j][nc] (8 scalar loads).
// C/D: col=lane&15, row=q*4+reg  (m89-verified mapping).
__device__ __forceinline__ f32x4 mm16f(const float* __restrict__ A, const float* __restrict__ B,
                                       int lda, int ldb, int K, int mr, int nc, int lane){
  int q = lane >> 4;
  f32x4 acc = {0.f,0.f,0.f,0.f};
  const float* ap = A + (size_t)mr*lda + q*8;
  const float* bp = B + (size_t)(q*8)*ldb + nc;
#pragma unroll 2
  for(int k0 = 0; k0 < K; k0 += 32){
    f32x4 a0 = *(const f32x4*)ap;
    f32x4 a1 = *(const f32x4*)(ap+4);
    bf16x8 a, b;
#pragma unroll
    for(int j=0;j<4;j++){ a[j] = (bf16)a0[j]; a[4+j] = (bf16)a1[j]; }
#pragma unroll
    for(int j=0;j<8;j++) b[j] = (bf16)bp[(size_t)j*ldb];
    acc = __builtin_amdgcn_mfma_f32_16x16x32_bf16(a, b, acc, 0, 0, 0);
    ap += 32; bp += (size_t)32*ldb;
  }
  return acc;
}

// ---- x1=[emb[x[b]]|query[b]] fp32; outc[768:1280]=cat_dec
__global__ void k_prep(const int* __restrict__ x, const float* __restrict__ query,
                       const float* __restrict__ emb, const float* __restrict__ catd,
                       float* __restrict__ x1, float* __restrict__ outc){
  int b = blockIdx.x, t = threadIdx.x;  // 256 thr
  int row = x[b];
  x1[b*512 + t]       = emb[(size_t)row*EMB + t];
  x1[b*512 + 256 + t] = query[(size_t)b*256 + t];
  outc[b*KCAT + 768 + t]       = catd[(size_t)b*512 + t];
  outc[b*KCAT + 768 + 256 + t] = catd[(size_t)b*512 + 256 + t];
}

// ---- C[64,N] = A[64,K] @ B[K,N]; grid N/16, 256 thr = 4 m-waves
__global__ __launch_bounds__(256) void k_gemm_mf(const float* __restrict__ A, const float* __restrict__ B,
                                                 float* __restrict__ C, int K, int N){
  int lane = threadIdx.x & 63, w = threadIdx.x >> 6;
  int col = blockIdx.x*16 + (lane & 15);
  f32x4 acc = mm16f(A, B, K, N, K, w*16 + (lane & 15), col, lane);
  int rb = w*16 + (lane >> 4)*4;
#pragma unroll
  for(int r=0;r<4;r++) C[(size_t)(rb+r)*N + col] = acc[r];
}

// ---- GRU gates (keras reset_after=True, z/r/h); h0 = dec_hidden input (fp32)
__global__ void k_gates(const float* __restrict__ xm, const float* __restrict__ hm,
                        const float* __restrict__ bias, const float* __restrict__ h0,
                        float* __restrict__ hn, float* __restrict__ outc, float* __restrict__ dout){
  int b = blockIdx.x, u = threadIdx.x;  // 512 thr
  const float* xr = xm + b*1536; const float* hr = hm + b*1536;
  float xz = xr[u]      + bias[u];
  float xg = xr[512+u]  + bias[512+u];
  float xh = xr[1024+u] + bias[1024+u];
  float hz = hr[u]      + bias[1536+u];
  float hg = hr[512+u]  + bias[2048+u];
  float hh = hr[1024+u] + bias[2560+u];
  float z = rcp_(1.f + exp2_(-L2E*(xz+hz)));
  float r = rcp_(1.f + exp2_(-L2E*(xg+hg)));
  float ca = xh + r*hh;
  ca = fminf(fmaxf(ca, -15.f), 15.f);
  float e = exp2_(2.f*L2E*ca);
  float hc = (e - 1.f)*rcp_(e + 1.f);
  float h = h0[b*512+u];
  float v = z*h + (1.f - z)*hc;
  hn[b*512+u] = v;
  outc[b*KCAT + 256 + u] = v;
  dout[(size_t)POI*BB + (size_t)b*512 + u] = v;                       // state
  dout[(size_t)POI*BB + (size_t)BB*512 + (size_t)b*512 + u] = v;      // output_
}

// ---- Eq = exp2(clamp(2*log2e*(hn@W2 + b2))) : [64,512] fp32. grid 32.
__global__ __launch_bounds__(256) void k_qproj(const float* __restrict__ hn, const float* __restrict__ W2,
                        const float* __restrict__ W2b, float* __restrict__ Eq){
  int lane = threadIdx.x & 63, w = threadIdx.x >> 6;
  int col = blockIdx.x*16 + (lane & 15);
  f32x4 acc = mm16f(hn, W2, UNITS, UNITS, UNITS, w*16 + (lane & 15), col, lane);
  float bn = W2b[col];
  int rb = w*16 + (lane >> 4)*4;
#pragma unroll
  for(int r=0;r<4;r++){
    float v = (acc[r] + bn)*(2.f*L2E);
    Eq[(rb+r)*UNITS + col] = exp2_(fminf(fmaxf(v, -40.f), 40.f));
  }
}

// ---- fused vproj+score, 16 poi rows/block. stage1 MFMA -> Ev in LDS;
// stage2: sc[b][p] = sum_u Vw[u]/(Ev[p][u]*Eq[b][u]+1)  (tanh identity in k_softmax)
__global__ __launch_bounds__(256) void k_vscore(const float* __restrict__ emb, const float* __restrict__ W1,
    const float* __restrict__ W1b, const float* __restrict__ Eq,
    const float* __restrict__ Vw, float* __restrict__ sc){
  __shared__ float evs[16][516];
  __shared__ float Qs[64][68];
  __shared__ float vws[512];
  int t = threadIdx.x, lane = t & 63, w = t >> 6;
  int p0 = blockIdx.x*16;
  int mr = p0 + (lane & 15); if(mr > POI-1) mr = POI-1;   // tail clamp
#pragma unroll
  for(int i=0;i<8;i++){
    int nc = w*16 + i*64 + (lane & 15);                    // 4 waves x 8 tiles = 32 col-tiles
    f32x4 acc = mm16f(emb, W1, EMB, UNITS, EMB, mr, nc, lane);
    float bn = W1b[nc];
    int rb = (lane >> 4)*4;
#pragma unroll
    for(int r=0;r<4;r++){
      float v = (acc[r] + bn)*(2.f*L2E);
      evs[rb+r][nc] = exp2_(fminf(fmaxf(v, -40.f), 40.f));
    }
  }
  int tp = t & 7, tb = t >> 3;
  float s00=0.f, s01=0.f, s10=0.f, s11=0.f;
  for(int c=0;c<8;c++){
    __syncthreads();                 // c=0: evs complete; c>0: Qs consumers done
    int ub = c*64;
    for(int i=t;i<4096;i+=256){ int b=i>>6, u=i&63; Qs[b][u] = Eq[b*UNITS + ub + u]; }
    if(c==0){ vws[t] = Vw[t]; vws[t+256] = Vw[t+256]; }
    __syncthreads();
#pragma unroll
    for(int u4=0;u4<16;u4++){
      f32x4 e0 = *(f32x4*)&evs[2*tp][ub+u4*4];
      f32x4 e1 = *(f32x4*)&evs[2*tp+1][ub+u4*4];
      f32x4 q0 = *(f32x4*)&Qs[2*tb][u4*4];
      f32x4 q1 = *(f32x4*)&Qs[2*tb+1][u4*4];
      f32x4 w4 = *(f32x4*)&vws[ub+u4*4];
#pragma unroll
      for(int e=0;e<4;e++){
        float wv = w4[e];
        s00 += wv * rcp_(e0[e]*q0[e] + 1.f);
        s01 += wv * rcp_(e0[e]*q1[e] + 1.f);
        s10 += wv * rcp_(e1[e]*q0[e] + 1.f);
        s11 += wv * rcp_(e1[e]*q1[e] + 1.f);
      }
    }
  }
  int pA = p0 + 2*tp, bA = 2*tb;
  if(pA < POI)  { sc[(size_t)bA*SCLD + pA]   = s00; sc[(size_t)(bA+1)*SCLD + pA]   = s01; }
  if(pA+1 < POI){ sc[(size_t)bA*SCLD + pA+1] = s10; sc[(size_t)(bA+1)*SCLD + pA+1] = s11; }
}

// ---- per-b: s = SW-2*sc; softmax; write NORMALIZED weights back; zero pad; zero outc ctx region
__global__ void k_softmax(float* __restrict__ sc, const float* __restrict__ Vw, float* __restrict__ outc){
  __shared__ float red[256];
  int b = blockIdx.x, t = threadIdx.x;
  outc[b*KCAT + t] = 0.f;                    // zero ctx accumulator region
  red[t] = Vw[t] + Vw[t+256];
  __syncthreads();
  for(int o=128;o>0;o>>=1){ if(t<o) red[t]+=red[t+o]; __syncthreads(); }
  float SW = red[0]; __syncthreads();
  float* sA = sc + (size_t)b*SCLD;
  float mx = -3.4e38f;
  for(int p=t;p<POI;p+=256){
    float s = SW - 2.f*sA[p];
    sA[p] = s;
    mx = fmaxf(mx, s);
  }
  red[t] = mx; __syncthreads();
  for(int o=128;o>0;o>>=1){ if(t<o) red[t]=fmaxf(red[t],red[t+o]); __syncthreads(); }
  float M = red[0]; __syncthreads();
  float sum = 0.f;
  for(int p=t;p<POI;p+=256){
    float wv = exp2_((sA[p] - M)*L2E);
    sA[p] = wv;
    sum += wv;
  }
  red[t] = sum; __syncthreads();
  for(int o=128;o>0;o>>=1){ if(t<o) red[t]+=red[t+o]; __syncthreads(); }
  float iv = rcp_(red[0]);
  for(int p=t;p<POI;p+=256) sA[p] *= iv;     // normalized attention weights
  if(t < SCLD-POI) sA[POI + t] = 0.f;        // zero k-pad for ctx GEMM
}

// ---- context = wb[64,5024] @ emb[5000,256] (split-K, atomic fp32) -> outc[:,0:256]
__global__ __launch_bounds__(256) void k_ctx(const float* __restrict__ wb, const float* __restrict__ emb,
                                             float* __restrict__ outc){
  int lane = threadIdx.x & 63, w = threadIdx.x >> 6;
  int n = blockIdx.x*16 + (lane & 15);       // n < 256
  int ky = blockIdx.y;                        // 13 splits of 12 k-steps (384)
  int kbeg = ky*384;
  int mr = w*16 + (lane & 15);
  f32x4 acc = mm16f(wb + kbeg, emb + (size_t)kbeg*EMB, SCLD, EMB, 384, mr, n, lane);
  if(ky == 12){                               // clamped tail step [4992,5024): wb pad=0
    int q = lane >> 4;
    const float* ap = wb + (size_t)mr*SCLD + 4992 + q*8;
    bf16x8 a, bfr;
#pragma unroll
    for(int j=0;j<8;j++) a[j] = (bf16)ap[j];
#pragma unroll
    for(int j=0;j<8;j++){
      int k = 4992 + q*8 + j; int kc = k < POI ? k : POI-1;
      bfr[j] = (bf16)emb[(size_t)kc*EMB + n];
    }
    acc = __builtin_amdgcn_mfma_f32_16x16x32_bf16(a, bfr, acc, 0, 0, 0);
  }
  int rb = w*16 + (lane >> 4)*4;
#pragma unroll
  for(int r=0;r<4;r++) atomicAdd(&outc[(size_t)(rb+r)*KCAT + n], acc[r]);
}

// ---- logits = outc @ fc_w + fc_b -> d_out fp32. grid 313.
__global__ __launch_bounds__(256) void k_logits(const float* __restrict__ A, const float* __restrict__ Bw,
                        const float* __restrict__ fcb, float* __restrict__ out){
  int lane = threadIdx.x & 63, w = threadIdx.x >> 6;
  int n = blockIdx.x*16 + (lane & 15);
  int nc = n < POI ? n : POI-1;
  f32x4 acc = mm16f(A, Bw, KCAT, POI, KCAT, w*16 + (lane & 15), nc, lane);
  int rb = w*16 + (lane >> 4)*4;
  if(n < POI){
    float bn = fcb[n];
#pragma unroll
    for(int r=0;r<4;r++) out[(size_t)(rb+r)*POI + n] = acc[r] + bn;
  }
}

extern "C" void kernel_launch(void* const* d_in, const int* in_sizes, int n_in,
                              void* d_out, int out_size, void* d_ws, size_t ws_size,
                              hipStream_t stream){
  const int*   x     = (const int*)d_in[0];
  const float* query = (const float*)d_in[1];
  const float* emb   = (const float*)d_in[2];
  // d_in[3] A_hat unused by reference
  const float* h0    = (const float*)d_in[4];
  const float* catd  = (const float*)d_in[5];
  const float* gruK  = (const float*)d_in[6];
  const float* gruR  = (const float*)d_in[7];
  const float* gruB  = (const float*)d_in[8];
  const float* W1    = (const float*)d_in[9];
  const float* W1b   = (const float*)d_in[10];
  const float* W2    = (const float*)d_in[11];
  const float* W2b   = (const float*)d_in[12];
  const float* Vw    = (const float*)d_in[13];
  // d_in[14] V_b: softmax-invariant, dropped
  const float* fcw   = (const float*)d_in[15];
  const float* fcb   = (const float*)d_in[16];
  float* out = (float*)d_out;

  char* ws = (char*)d_ws;
  size_t off = 0;
  auto alloc = [&](size_t bytes)->void*{ void* p = ws + off; off += (bytes + 255) & ~(size_t)255; return p; };
  float* x1   = (float*)alloc((size_t)BB*512*4);
  float* outc = (float*)alloc((size_t)BB*KCAT*4);
  float* xm   = (float*)alloc((size_t)BB*1536*4);
  float* hm   = (float*)alloc((size_t)BB*1536*4);
  float* hn   = (float*)alloc((size_t)BB*512*4);
  float* Eq   = (float*)alloc((size_t)BB*512*4);
  float* sc   = (float*)alloc((size_t)BB*SCLD*4);
  // total ~2.6 MB

  k_prep   <<<BB, 256, 0, stream>>>(x, query, emb, catd, x1, outc);
  k_gemm_mf<<<96, 256, 0, stream>>>(x1, gruK, xm, 512, 1536);
  k_gemm_mf<<<96, 256, 0, stream>>>(h0, gruR, hm, 512, 1536);
  k_gates  <<<BB, 512, 0, stream>>>(xm, hm, gruB, h0, hn, outc, out);
  k_qproj  <<<32, 256, 0, stream>>>(hn, W2, W2b, Eq);
  k_vscore <<<313, 256, 0, stream>>>(emb, W1, W1b, Eq, Vw, sc);
  k_softmax<<<BB, 256, 0, stream>>>(sc, Vw, outc);
  k_ctx    <<<dim3(16,13), 256, 0, stream>>>(sc, emb, outc);
  k_logits <<<313, 256, 0, stream>>>(outc, fcw, fcb, out);
}

// Round 5
// 198.463 us; speedup vs baseline: 7.9387x; 1.2739x over previous
//
#include <hip/hip_runtime.h>
#include <hip/hip_bf16.h>

typedef __bf16 bf16;
typedef __bf16 bf16x8 __attribute__((ext_vector_type(8)));
typedef float f32x4 __attribute__((ext_vector_type(4)));

#define BB 64
#define EMB 256
#define UNITS 512
#define POI 5000
#define KCAT 1280
#define SCLD 5024   // sc row stride (5000 padded to x32)
#define L2E 1.4426950408889634f

__device__ __forceinline__ float rcp_(float x){ return __builtin_amdgcn_rcpf(x); }
__device__ __forceinline__ float exp2_(float x){ return __builtin_amdgcn_exp2f(x); }

// ---- one 16x16x(K) MFMA C-tile from fp32 sources, on-the-fly bf16 cvt.
// A fp32 row-major [*, lda]: lane -> A[mr][q*8+j]. B fp32 row-major [K, ldb]: lane -> B[q*8+j][nc].
// C/D: col=lane&15, row=q*4+reg (m89-verified; validated in R3/R4 pass).
__device__ __forceinline__ f32x4 mm16f(const float* __restrict__ A, const float* __restrict__ B,
                                       int lda, int ldb, int K, int mr, int nc, int lane){
  int q = lane >> 4;
  f32x4 acc = {0.f,0.f,0.f,0.f};
  const float* ap = A + (size_t)mr*lda + q*8;
  const float* bp = B + (size_t)(q*8)*ldb + nc;
#pragma unroll 2
  for(int k0 = 0; k0 < K; k0 += 32){
    f32x4 a0 = *(const f32x4*)ap;
    f32x4 a1 = *(const f32x4*)(ap+4);
    bf16x8 a, b;
#pragma unroll
    for(int j=0;j<4;j++){ a[j] = (bf16)a0[j]; a[4+j] = (bf16)a1[j]; }
#pragma unroll
    for(int j=0;j<8;j++) b[j] = (bf16)bp[(size_t)j*ldb];
    acc = __builtin_amdgcn_mfma_f32_16x16x32_bf16(a, b, acc, 0, 0, 0);
    ap += 32; bp += (size_t)32*ldb;
  }
  return acc;
}

// ---- x1=[emb[x[b]]|query[b]] fp32; outc[768:1280]=cat_dec
__global__ void k_prep(const int* __restrict__ x, const float* __restrict__ query,
                       const float* __restrict__ emb, const float* __restrict__ catd,
                       float* __restrict__ x1, float* __restrict__ outc){
  int b = blockIdx.x, t = threadIdx.x;  // 256 thr
  int row = x[b];
  x1[b*512 + t]       = emb[(size_t)row*EMB + t];
  x1[b*512 + 256 + t] = query[(size_t)b*256 + t];
  outc[b*KCAT + 768 + t]       = catd[(size_t)b*512 + t];
  outc[b*KCAT + 768 + 256 + t] = catd[(size_t)b*512 + 256 + t];
}

// ---- merged GRU GEMMs, split-K x2: grid (96, 2, 2). y: 0=x1@gruK, 1=h0@gruR. z: k-half.
__global__ __launch_bounds__(256) void k_gru(const float* __restrict__ x1, const float* __restrict__ h0,
    const float* __restrict__ gruK, const float* __restrict__ gruR,
    float* __restrict__ xmP, float* __restrict__ hmP){
  int lane = threadIdx.x & 63, w = threadIdx.x >> 6;
  int col = blockIdx.x*16 + (lane & 15);
  const float* A = blockIdx.y ? h0 : x1;
  const float* B = blockIdx.y ? gruR : gruK;
  float* C = (blockIdx.y ? hmP : xmP) + (size_t)blockIdx.z*BB*1536;
  int z = blockIdx.z;
  f32x4 acc = mm16f(A + z*256, B + (size_t)(z*256)*1536, 512, 1536, 256,
                    w*16 + (lane & 15), col, lane);
  int rb = w*16 + (lane >> 4)*4;
#pragma unroll
  for(int r=0;r<4;r++) C[(size_t)(rb+r)*1536 + col] = acc[r];
}

// ---- GRU gates (keras reset_after=True, z/r/h); sums the 2 k-split slabs
__global__ void k_gates(const float* __restrict__ xmP, const float* __restrict__ hmP,
                        const float* __restrict__ bias, const float* __restrict__ h0,
                        float* __restrict__ hn, float* __restrict__ outc, float* __restrict__ dout){
  int b = blockIdx.x, u = threadIdx.x;  // 512 thr
  const float* x0 = xmP + b*1536; const float* x1s = xmP + (size_t)BB*1536 + b*1536;
  const float* h0s = hmP + b*1536; const float* h1s = hmP + (size_t)BB*1536 + b*1536;
  float xz = x0[u]      + x1s[u]      + bias[u];
  float xg = x0[512+u]  + x1s[512+u]  + bias[512+u];
  float xh = x0[1024+u] + x1s[1024+u] + bias[1024+u];
  float hz = h0s[u]      + h1s[u]      + bias[1536+u];
  float hg = h0s[512+u]  + h1s[512+u]  + bias[2048+u];
  float hh = h0s[1024+u] + h1s[1024+u] + bias[2560+u];
  float z = rcp_(1.f + exp2_(-L2E*(xz+hz)));
  float r = rcp_(1.f + exp2_(-L2E*(xg+hg)));
  float ca = xh + r*hh;
  ca = fminf(fmaxf(ca, -15.f), 15.f);
  float e = exp2_(2.f*L2E*ca);
  float hc = (e - 1.f)*rcp_(e + 1.f);
  float h = h0[b*512+u];
  float v = z*h + (1.f - z)*hc;
  hn[b*512+u] = v;
  outc[b*KCAT + 256 + u] = v;
  dout[(size_t)POI*BB + (size_t)b*512 + u] = v;                       // state
  dout[(size_t)POI*BB + (size_t)BB*512 + (size_t)b*512 + u] = v;      // output_
}

// ---- Eq = exp2(clamp(2*log2e*(hn@W2 + b2))) : [64,512]. grid 32.
__global__ __launch_bounds__(256) void k_qproj(const float* __restrict__ hn, const float* __restrict__ W2,
                        const float* __restrict__ W2b, float* __restrict__ Eq){
  int lane = threadIdx.x & 63, w = threadIdx.x >> 6;
  int col = blockIdx.x*16 + (lane & 15);
  f32x4 acc = mm16f(hn, W2, UNITS, UNITS, UNITS, w*16 + (lane & 15), col, lane);
  float bn = W2b[col];
  int rb = w*16 + (lane >> 4)*4;
#pragma unroll
  for(int r=0;r<4;r++){
    float v = (acc[r] + bn)*(2.f*L2E);
    Eq[(rb+r)*UNITS + col] = exp2_(fminf(fmaxf(v, -40.f), 40.f));
  }
}

// ---- fused vproj+score, grid (313, 4): 16 poi rows x 128-u quarter per block.
// stage1 MFMA -> Ev quarter in LDS (partitioned, no redundancy);
// stage2: sc_y[b][p] = sum_{u in quarter} Vw[u]/(Ev[p][u]*Eq[b][u]+1)
__global__ __launch_bounds__(256) void k_vscore(const float* __restrict__ emb, const float* __restrict__ W1,
    const float* __restrict__ W1b, const float* __restrict__ Eq,
    const float* __restrict__ Vw, float* __restrict__ scS){
  __shared__ float evs[16][132];
  __shared__ float Qs[64][68];
  __shared__ float vws[128];
  int t = threadIdx.x, lane = t & 63, w = t >> 6;
  int p0 = blockIdx.x*16, uh = blockIdx.y*128;
  int mr = p0 + (lane & 15); if(mr > POI-1) mr = POI-1;   // tail clamp
#pragma unroll
  for(int i=0;i<2;i++){
    int ncl = (w + i*4)*16 + (lane & 15);                  // local col 0..127
    f32x4 acc = mm16f(emb, W1, EMB, UNITS, EMB, mr, uh + ncl, lane);
    float bn = W1b[uh + ncl];
    int rb = (lane >> 4)*4;
#pragma unroll
    for(int r=0;r<4;r++){
      float v = (acc[r] + bn)*(2.f*L2E);
      evs[rb+r][ncl] = exp2_(fminf(fmaxf(v, -40.f), 40.f));
    }
  }
  if(t < 128) vws[t] = Vw[uh + t];
  int tp = t & 7, tb = t >> 3;
  float s00=0.f, s01=0.f, s10=0.f, s11=0.f;
  for(int c=0;c<2;c++){
    __syncthreads();                 // c=0: evs/vws complete; c=1: Qs consumers done
    int ub = c*64;
    for(int i=t;i<4096;i+=256){ int b=i>>6, u=i&63; Qs[b][u] = Eq[b*UNITS + uh + ub + u]; }
    __syncthreads();
#pragma unroll
    for(int u4=0;u4<16;u4++){
      f32x4 e0 = *(f32x4*)&evs[2*tp][ub+u4*4];
      f32x4 e1 = *(f32x4*)&evs[2*tp+1][ub+u4*4];
      f32x4 q0 = *(f32x4*)&Qs[2*tb][u4*4];
      f32x4 q1 = *(f32x4*)&Qs[2*tb+1][u4*4];
      f32x4 w4 = *(f32x4*)&vws[ub+u4*4];
#pragma unroll
      for(int e=0;e<4;e++){
        float wv = w4[e];
        s00 += wv * rcp_(e0[e]*q0[e] + 1.f);
        s01 += wv * rcp_(e0[e]*q1[e] + 1.f);
        s10 += wv * rcp_(e1[e]*q0[e] + 1.f);
        s11 += wv * rcp_(e1[e]*q1[e] + 1.f);
      }
    }
  }
  float* s = scS + (size_t)blockIdx.y*BB*SCLD;
  int pA = p0 + 2*tp, bA = 2*tb;
  if(pA < POI)  { s[(size_t)bA*SCLD + pA]   = s00; s[(size_t)(bA+1)*SCLD + pA]   = s01; }
  if(pA+1 < POI){ s[(size_t)bA*SCLD + pA+1] = s10; s[(size_t)(bA+1)*SCLD + pA+1] = s11; }
}

// ---- per-b: s = SW - 2*sum_y(sc_y); softmax; normalized weights into slab0; zero pad + outc ctx
__global__ __launch_bounds__(512) void k_softmax(float* __restrict__ sc, const float* __restrict__ Vw,
                                                 float* __restrict__ outc){
  __shared__ float red[512];
  int b = blockIdx.x, t = threadIdx.x;
  if(t < 256) outc[b*KCAT + t] = 0.f;        // zero ctx accumulator region
  red[t] = Vw[t];
  __syncthreads();
  for(int o=256;o>0;o>>=1){ if(t<o) red[t]+=red[t+o]; __syncthreads(); }
  float SW = red[0]; __syncthreads();
  float* sA = sc + (size_t)b*SCLD;
  const float* s1 = sA + (size_t)BB*SCLD;
  const float* s2 = sA + (size_t)2*BB*SCLD;
  const float* s3 = sA + (size_t)3*BB*SCLD;
  float mx = -3.4e38f;
  for(int p=t;p<POI;p+=512){
    float s = SW - 2.f*(sA[p] + s1[p] + s2[p] + s3[p]);
    sA[p] = s;
    mx = fmaxf(mx, s);
  }
  red[t] = mx; __syncthreads();
  for(int o=256;o>0;o>>=1){ if(t<o) red[t]=fmaxf(red[t],red[t+o]); __syncthreads(); }
  float M = red[0]; __syncthreads();
  float sum = 0.f;
  for(int p=t;p<POI;p+=512){
    float wv = exp2_((sA[p] - M)*L2E);
    sA[p] = wv;
    sum += wv;
  }
  red[t] = sum; __syncthreads();
  for(int o=256;o>0;o>>=1){ if(t<o) red[t]+=red[t+o]; __syncthreads(); }
  float iv = rcp_(red[0]);
  for(int p=t;p<POI;p+=512) sA[p] *= iv;     // normalized attention weights
  if(t < SCLD-POI) sA[POI + t] = 0.f;        // zero k-pad for ctx GEMM
}

// ---- context = wb[64,5024] @ emb[5000,256] (split-K x13, atomic) -> outc[:,0:256]
__global__ __launch_bounds__(256) void k_ctx(const float* __restrict__ wb, const float* __restrict__ emb,
                                             float* __restrict__ outc){
  int lane = threadIdx.x & 63, w = threadIdx.x >> 6;
  int n = blockIdx.x*16 + (lane & 15);       // n < 256
  int ky = blockIdx.y;                        // 13 splits of 384
  int kbeg = ky*384;
  int mr = w*16 + (lane & 15);
  f32x4 acc = mm16f(wb + kbeg, emb + (size_t)kbeg*EMB, SCLD, EMB, 384, mr, n, lane);
  if(ky == 12){                               // tail [4992,5024): wb pad=0, emb row clamped
    int q = lane >> 4;
    const float* ap = wb + (size_t)mr*SCLD + 4992 + q*8;
    bf16x8 a, bfr;
#pragma unroll
    for(int j=0;j<8;j++) a[j] = (bf16)ap[j];
#pragma unroll
    for(int j=0;j<8;j++){
      int k = 4992 + q*8 + j; int kc = k < POI ? k : POI-1;
      bfr[j] = (bf16)emb[(size_t)kc*EMB + n];
    }
    acc = __builtin_amdgcn_mfma_f32_16x16x32_bf16(a, bfr, acc, 0, 0, 0);
  }
  int rb = w*16 + (lane >> 4)*4;
#pragma unroll
  for(int r=0;r<4;r++) atomicAdd(&outc[(size_t)(rb+r)*KCAT + n], acc[r]);
}

// ---- logits: split-K x4, atomicAdd into zeroed d_out; bias folded into split 0. grid (313,4).
__global__ __launch_bounds__(256) void k_logits(const float* __restrict__ A, const float* __restrict__ Bw,
                        const float* __restrict__ fcb, float* __restrict__ out){
  int lane = threadIdx.x & 63, w = threadIdx.x >> 6;
  int n = blockIdx.x*16 + (lane & 15);
  int nc = n < POI ? n : POI-1;
  int ky = blockIdx.y, kbeg = ky*320;         // 4 x 320 = 1280
  f32x4 acc = mm16f(A + kbeg, Bw + (size_t)kbeg*POI, KCAT, POI, 320,
                    w*16 + (lane & 15), nc, lane);
  int rb = w*16 + (lane >> 4)*4;
  if(n < POI){
    float bn = (ky == 0) ? fcb[n] : 0.f;
#pragma unroll
    for(int r=0;r<4;r++) atomicAdd(&out[(size_t)(rb+r)*POI + n], acc[r] + bn);
  }
}

extern "C" void kernel_launch(void* const* d_in, const int* in_sizes, int n_in,
                              void* d_out, int out_size, void* d_ws, size_t ws_size,
                              hipStream_t stream){
  const int*   x     = (const int*)d_in[0];
  const float* query = (const float*)d_in[1];
  const float* emb   = (const float*)d_in[2];
  // d_in[3] A_hat unused by reference
  const float* h0    = (const float*)d_in[4];
  const float* catd  = (const float*)d_in[5];
  const float* gruK  = (const float*)d_in[6];
  const float* gruR  = (const float*)d_in[7];
  const float* gruB  = (const float*)d_in[8];
  const float* W1    = (const float*)d_in[9];
  const float* W1b   = (const float*)d_in[10];
  const float* W2    = (const float*)d_in[11];
  const float* W2b   = (const float*)d_in[12];
  const float* Vw    = (const float*)d_in[13];
  // d_in[14] V_b: softmax-invariant, dropped
  const float* fcw   = (const float*)d_in[15];
  const float* fcb   = (const float*)d_in[16];
  float* out = (float*)d_out;

  char* ws = (char*)d_ws;
  size_t off = 0;
  auto alloc = [&](size_t bytes)->void*{ void* p = ws + off; off += (bytes + 255) & ~(size_t)255; return p; };
  float* x1   = (float*)alloc((size_t)BB*512*4);
  float* outc = (float*)alloc((size_t)BB*KCAT*4);
  float* xmP  = (float*)alloc((size_t)2*BB*1536*4);
  float* hmP  = (float*)alloc((size_t)2*BB*1536*4);
  float* hn   = (float*)alloc((size_t)BB*512*4);
  float* Eq   = (float*)alloc((size_t)BB*512*4);
  float* sc   = (float*)alloc((size_t)4*BB*SCLD*4);   // 4 u-quarter slabs
  // total ~7.5 MB

  hipMemsetAsync(out, 0, (size_t)BB*POI*sizeof(float), stream);  // logits accumulator
  k_prep   <<<BB, 256, 0, stream>>>(x, query, emb, catd, x1, outc);
  k_gru    <<<dim3(96,2,2), 256, 0, stream>>>(x1, h0, gruK, gruR, xmP, hmP);
  k_gates  <<<BB, 512, 0, stream>>>(xmP, hmP, gruB, h0, hn, outc, out);
  k_qproj  <<<32, 256, 0, stream>>>(hn, W2, W2b, Eq);
  k_vscore <<<dim3(313,4), 256, 0, stream>>>(emb, W1, W1b, Eq, Vw, sc);
  k_softmax<<<BB, 512, 0, stream>>>(sc, Vw, outc);
  k_ctx    <<<dim3(16,13), 256, 0, stream>>>(sc, emb, outc);
  k_logits <<<dim3(313,4), 256, 0, stream>>>(outc, fcw, fcb, out);
}